// Round 1
// baseline (522.555 us; speedup 1.0000x reference)
//
#include <hip/hip_runtime.h>
#include <math.h>

#define NROWS 16384
#define DIN   1024
#define DEMB  256
#define KC    1024
#define ALPHA 0.01f
#define EPSV  1e-5f

// ---- workspace layout (float-element offsets) ----
#define OFF_Z      0          // NROWS*DEMB        = 4194304
#define OFF_R      4194304    // KC*DIN            = 1048576
#define OFF_SQR    5242880    // KC                = 1024
#define OFF_PVAL   5243904    // NROWS*16          = 262144
#define OFF_UPD    5506048    // KC*DEMB           = 262144   (zeroed)
#define OFF_COUNTS 5768192    // KC                = 1024     (zeroed)
#define OFF_LOSS   5769216    // 16                           (zeroed)
#define OFF_SIZE   5769232    // KC                = 1024
#define OFF_PIDX   5770256    // NROWS*16 ints     = 262144
#define OFF_CODES  6032400    // NROWS ints        = 16384
// total ~6.05M floats ~24.2 MB

// ---- output layout (float-element offsets) ----
#define OUT_X      0           // NROWS*DIN = 16777216
#define OUT_CODES  16777216    // NROWS
#define OUT_EMB    16793600
#define OUT_COMMIT 16793601
#define OUT_ENT    16793602
#define OUT_EMAV   16793603    // KC*DEMB
#define OUT_EMAS   17055747    // KC
#define OUT_W      17056771    // KC*DEMB

// ---------------------------------------------------------------------------
// sqr[k] = sum_j codebook[k][j]^2   (one wave per code)
__global__ __launch_bounds__(64) void sqr_kernel(const float* __restrict__ cb,
                                                 float* __restrict__ sqr) {
    int k = blockIdx.x;
    int lane = threadIdx.x;
    float4 v = ((const float4*)cb)[k * 64 + lane];
    float s = v.x * v.x + v.y * v.y + v.z * v.z + v.w * v.w;
    for (int off = 32; off > 0; off >>= 1) s += __shfl_down(s, off, 64);
    if (lane == 0) sqr[k] = s;
}

// ---------------------------------------------------------------------------
// C[M,Nc] = A[M,Kd] @ B[Kd,Nc] (+ bias). Tile 128x64, 256 thr, 8x4/thread.
__global__ __launch_bounds__(256) void gemm_kernel(const float* __restrict__ A,
                                                   const float* __restrict__ B,
                                                   const float* __restrict__ bias,
                                                   float* __restrict__ C,
                                                   int M, int Kd, int Nc) {
    __shared__ float As[16][132];   // [d][row], pad 4 -> 2-way max on stores
    __shared__ float Bs[16][64];    // [d][col]
    const int tid = threadIdx.x;
    const int tx = tid & 15, ty = tid >> 4;
    const int rowBase = blockIdx.y * 128;
    const int colBase = blockIdx.x * 64;

    float acc[8][4];
#pragma unroll
    for (int i = 0; i < 8; ++i)
#pragma unroll
        for (int j = 0; j < 4; ++j) acc[i][j] = 0.f;

    const int a_row = tid >> 2;          // 0..63
    const int a_c4  = (tid & 3) * 4;     // 0,4,8,12
    const int b_r   = tid >> 4;          // 0..15
    const int b_c4  = (tid & 15) * 4;    // 0..60

    for (int kk = 0; kk < Kd; kk += 16) {
        float4 av0 = *(const float4*)&A[(size_t)(rowBase + a_row) * Kd + kk + a_c4];
        float4 av1 = *(const float4*)&A[(size_t)(rowBase + a_row + 64) * Kd + kk + a_c4];
        float4 bv  = *(const float4*)&B[(size_t)(kk + b_r) * Nc + colBase + b_c4];
        __syncthreads();
        As[a_c4 + 0][a_row] = av0.x;  As[a_c4 + 1][a_row] = av0.y;
        As[a_c4 + 2][a_row] = av0.z;  As[a_c4 + 3][a_row] = av0.w;
        As[a_c4 + 0][a_row + 64] = av1.x;  As[a_c4 + 1][a_row + 64] = av1.y;
        As[a_c4 + 2][a_row + 64] = av1.z;  As[a_c4 + 3][a_row + 64] = av1.w;
        *(float4*)&Bs[b_r][b_c4] = bv;
        __syncthreads();
#pragma unroll
        for (int d = 0; d < 16; ++d) {
            float4 a01 = *(const float4*)&As[d][ty * 8];
            float4 a23 = *(const float4*)&As[d][ty * 8 + 4];
            float4 b01 = *(const float4*)&Bs[d][tx * 4];
            float a[8] = {a01.x, a01.y, a01.z, a01.w, a23.x, a23.y, a23.z, a23.w};
            float b[4] = {b01.x, b01.y, b01.z, b01.w};
#pragma unroll
            for (int i = 0; i < 8; ++i)
#pragma unroll
                for (int j = 0; j < 4; ++j) acc[i][j] += a[i] * b[j];
        }
    }

    float4 bb = make_float4(0.f, 0.f, 0.f, 0.f);
    if (bias) bb = *(const float4*)&bias[colBase + tx * 4];
#pragma unroll
    for (int i = 0; i < 8; ++i) {
        int r = rowBase + ty * 8 + i;
        float4 o = make_float4(acc[i][0] + bb.x, acc[i][1] + bb.y,
                               acc[i][2] + bb.z, acc[i][3] + bb.w);
        *(float4*)&C[(size_t)r * Nc + colBase + tx * 4] = o;
    }
}

// ---------------------------------------------------------------------------
// cov tile + fused argmin partials. A=z[N,256], B=codebook[K,256] (both
// row-major, inner product over d). score = sqr[k] - 2*cov. Writes per
// (row, col-tile) partial (minval, minidx).
__global__ __launch_bounds__(256) void cov_argmin_kernel(const float* __restrict__ Z,
                                                         const float* __restrict__ CB,
                                                         const float* __restrict__ sqr,
                                                         float* __restrict__ pval,
                                                         int* __restrict__ pidx) {
    __shared__ float As[16][132];   // [d][row]
    __shared__ float Bs[16][68];    // [d][code], pad 4
    const int tid = threadIdx.x;
    const int tx = tid & 15, ty = tid >> 4;
    const int rowBase  = blockIdx.y * 128;
    const int codeBase = blockIdx.x * 64;

    float acc[8][4];
#pragma unroll
    for (int i = 0; i < 8; ++i)
#pragma unroll
        for (int j = 0; j < 4; ++j) acc[i][j] = 0.f;

    const int a_row = tid >> 2;         // 0..63
    const int a_c4  = (tid & 3) * 4;

    for (int kk = 0; kk < DEMB; kk += 16) {
        float4 av0 = *(const float4*)&Z[(size_t)(rowBase + a_row) * DEMB + kk + a_c4];
        float4 av1 = *(const float4*)&Z[(size_t)(rowBase + a_row + 64) * DEMB + kk + a_c4];
        float4 bv  = *(const float4*)&CB[(size_t)(codeBase + a_row) * DEMB + kk + a_c4];
        __syncthreads();
        As[a_c4 + 0][a_row] = av0.x;  As[a_c4 + 1][a_row] = av0.y;
        As[a_c4 + 2][a_row] = av0.z;  As[a_c4 + 3][a_row] = av0.w;
        As[a_c4 + 0][a_row + 64] = av1.x;  As[a_c4 + 1][a_row + 64] = av1.y;
        As[a_c4 + 2][a_row + 64] = av1.z;  As[a_c4 + 3][a_row + 64] = av1.w;
        Bs[a_c4 + 0][a_row] = bv.x;  Bs[a_c4 + 1][a_row] = bv.y;
        Bs[a_c4 + 2][a_row] = bv.z;  Bs[a_c4 + 3][a_row] = bv.w;
        __syncthreads();
#pragma unroll
        for (int d = 0; d < 16; ++d) {
            float4 a01 = *(const float4*)&As[d][ty * 8];
            float4 a23 = *(const float4*)&As[d][ty * 8 + 4];
            float4 b01 = *(const float4*)&Bs[d][tx * 4];
            float a[8] = {a01.x, a01.y, a01.z, a01.w, a23.x, a23.y, a23.z, a23.w};
            float b[4] = {b01.x, b01.y, b01.z, b01.w};
#pragma unroll
            for (int i = 0; i < 8; ++i)
#pragma unroll
                for (int j = 0; j < 4; ++j) acc[i][j] += a[i] * b[j];
        }
    }

    float4 sq = *(const float4*)&sqr[codeBase + tx * 4];
    float sqa[4] = {sq.x, sq.y, sq.z, sq.w};
#pragma unroll
    for (int i = 0; i < 8; ++i) {
        float bvv = 3.4e38f; int bii = 0;
#pragma unroll
        for (int j = 0; j < 4; ++j) {
            float s = sqa[j] - 2.0f * acc[i][j];
            if (s < bvv) { bvv = s; bii = codeBase + tx * 4 + j; }   // ascending j: first-min
        }
        // reduce across 16 lanes of same ty (consecutive lanes; ascending tx = ascending code)
        for (int off = 8; off > 0; off >>= 1) {
            float ov = __shfl_down(bvv, off, 16);
            int   oi = __shfl_down(bii, off, 16);
            if (ov < bvv || (ov == bvv && oi < bii)) { bvv = ov; bii = oi; }
        }
        if (tx == 0) {
            int r = rowBase + ty * 8 + i;
            pval[r * 16 + blockIdx.x] = bvv;
            pidx[r * 16 + blockIdx.x] = bii;
        }
    }
}

// ---------------------------------------------------------------------------
__global__ __launch_bounds__(256) void argmin_reduce_kernel(const float* __restrict__ pval,
                                                            const int* __restrict__ pidx,
                                                            int* __restrict__ codes,
                                                            float* __restrict__ out_codes) {
    int r = blockIdx.x * 256 + threadIdx.x;
    if (r >= NROWS) return;
    float bv = pval[r * 16]; int bi = pidx[r * 16];
    for (int t = 1; t < 16; ++t) {        // ascending tile = ascending code range; strict <
        float v = pval[r * 16 + t]; int i = pidx[r * 16 + t];
        if (v < bv || (v == bv && i < bi)) { bv = v; bi = i; }
    }
    codes[r] = bi;
    out_codes[r] = (float)bi;
}

// ---------------------------------------------------------------------------
// gather codebook[code], accumulate loss, scatter-add z rows + counts
__global__ __launch_bounds__(256) void gather_kernel(const float* __restrict__ z,
                                                     const float* __restrict__ cb,
                                                     const int* __restrict__ codes,
                                                     float* __restrict__ upd,
                                                     float* __restrict__ counts,
                                                     float* __restrict__ loss) {
    const int tid = threadIdx.x;
    const int row = blockIdx.x * 4 + (tid >> 6);
    const int lane = tid & 63;
    const int code = codes[row];
    float4 zv = ((const float4*)(z + (size_t)row * DEMB))[lane];
    float4 cv = ((const float4*)(cb + (size_t)code * DEMB))[lane];
    float dx = zv.x - cv.x, dy = zv.y - cv.y, dz = zv.z - cv.z, dw = zv.w - cv.w;
    float l = dx * dx + dy * dy + dz * dz + dw * dw;
    float* u = upd + (size_t)code * DEMB + lane * 4;
    atomicAdd(u + 0, zv.x); atomicAdd(u + 1, zv.y);
    atomicAdd(u + 2, zv.z); atomicAdd(u + 3, zv.w);
    if (lane == 0) atomicAdd(&counts[code], 1.0f);
    __shared__ float red[256];
    red[tid] = l;
    __syncthreads();
    for (int s = 128; s > 0; s >>= 1) {
        if (tid < s) red[tid] += red[tid + s];
        __syncthreads();
    }
    if (tid == 0) atomicAdd(loss, red[0]);
}

// ---------------------------------------------------------------------------
// x[n] = R[codes[n]] + b_recv   (R = codebook @ W_recv)
__global__ __launch_bounds__(256) void recv_kernel(const float* __restrict__ R,
                                                   const float* __restrict__ brecv,
                                                   const int* __restrict__ codes,
                                                   float* __restrict__ out) {
    const int n = blockIdx.x;
    const int t = threadIdx.x;
    const int code = codes[n];
    float4 r = ((const float4*)(R + (size_t)code * DIN))[t];
    float4 b = ((const float4*)brecv)[t];
    ((float4*)(out + (size_t)n * DIN))[t] =
        make_float4(r.x + b.x, r.y + b.y, r.z + b.z, r.w + b.w);
}

// ---------------------------------------------------------------------------
// ema_size_new, n, coef, size[], entropy, scalar losses — one block of 1024
__global__ __launch_bounds__(1024) void ema_small_kernel(const float* __restrict__ ema_size,
                                                         const float* __restrict__ counts,
                                                         const float* __restrict__ loss,
                                                         float* __restrict__ size_ws,
                                                         float* __restrict__ out) {
    __shared__ float rn[1024];
    __shared__ float re[1024];
    const int k = threadIdx.x;
    float c  = counts[k];
    float es = ema_size[k];
    float esn = es + ALPHA * (c - es);
    out[OUT_EMAS + k] = esn;
    float p = c * (1.0f / (float)NROWS);
    rn[k] = esn;
    re[k] = (p > 0.f) ? p * logf(p) : 0.f;
    __syncthreads();
    for (int s = 512; s > 0; s >>= 1) {
        if (k < s) { rn[k] += rn[k + s]; re[k] += re[k + s]; }
        __syncthreads();
    }
    float n = rn[0];
    float coef = n / (n + (float)KC * EPSV);
    size_ws[k] = coef * (esn + EPSV);
    if (k == 0) {
        out[OUT_ENT] = -re[0] / logf(2.0f);
        float l = loss[0];
        out[OUT_EMB] = l;
        out[OUT_COMMIT] = l;
    }
}

// ---------------------------------------------------------------------------
__global__ __launch_bounds__(256) void emav_kernel(const float* __restrict__ ema_vecs,
                                                   const float* __restrict__ upd,
                                                   const float* __restrict__ size_ws,
                                                   float* __restrict__ out) {
    int idx = blockIdx.x * 256 + threadIdx.x;   // grid 1024 -> 262144
    float ev = ema_vecs[idx], uv = upd[idx];
    float evn = ev + ALPHA * (uv - ev);
    out[OUT_EMAV + idx] = evn;
    out[OUT_W + idx] = evn / size_ws[idx >> 8];
}

// ---------------------------------------------------------------------------
extern "C" void kernel_launch(void* const* d_in, const int* in_sizes, int n_in,
                              void* d_out, int out_size, void* d_ws, size_t ws_size,
                              hipStream_t stream) {
    const float* input    = (const float*)d_in[0];
    const float* W_send   = (const float*)d_in[1];
    const float* b_send   = (const float*)d_in[2];
    const float* W_recv   = (const float*)d_in[3];
    const float* b_recv   = (const float*)d_in[4];
    const float* codebook = (const float*)d_in[5];
    const float* ema_vecs = (const float*)d_in[6];
    const float* ema_size = (const float*)d_in[7];
    float* out = (float*)d_out;
    float* ws  = (float*)d_ws;
    int*   wsi = (int*)d_ws;

    // zero the atomic accumulators (upd_vecs | counts | loss are contiguous)
    hipMemsetAsync(ws + OFF_UPD, 0, (size_t)(262144 + 1024 + 16) * sizeof(float), stream);

    sqr_kernel<<<KC, 64, 0, stream>>>(codebook, ws + OFF_SQR);

    // z = input @ W_send + b_send   [16384,1024]x[1024,256]
    gemm_kernel<<<dim3(DEMB / 64, NROWS / 128), 256, 0, stream>>>(
        input, W_send, b_send, ws + OFF_Z, NROWS, DIN, DEMB);

    // R = codebook @ W_recv         [1024,256]x[256,1024]
    gemm_kernel<<<dim3(DIN / 64, KC / 128), 256, 0, stream>>>(
        codebook, W_recv, nullptr, ws + OFF_R, KC, DEMB, DIN);

    // cov + fused argmin partials
    cov_argmin_kernel<<<dim3(KC / 64, NROWS / 128), 256, 0, stream>>>(
        ws + OFF_Z, codebook, ws + OFF_SQR, ws + OFF_PVAL, wsi + OFF_PIDX);

    argmin_reduce_kernel<<<NROWS / 256, 256, 0, stream>>>(
        ws + OFF_PVAL, wsi + OFF_PIDX, wsi + OFF_CODES, out + OUT_CODES);

    gather_kernel<<<NROWS / 4, 256, 0, stream>>>(
        ws + OFF_Z, codebook, wsi + OFF_CODES,
        ws + OFF_UPD, ws + OFF_COUNTS, ws + OFF_LOSS);

    recv_kernel<<<NROWS, 256, 0, stream>>>(
        ws + OFF_R, b_recv, wsi + OFF_CODES, out + OUT_X);

    ema_small_kernel<<<1, 1024, 0, stream>>>(
        ema_size, ws + OFF_COUNTS, ws + OFF_LOSS, ws + OFF_SIZE, out);

    emav_kernel<<<KC, 256, 0, stream>>>(
        ema_vecs, ws + OFF_UPD, ws + OFF_SIZE, out);
}